// Round 8
// baseline (125.991 us; speedup 1.0000x reference)
//
#include <hip/hip_runtime.h>
#include <math.h>

constexpr int Dn = 4096;     // C*H*W (row length)
constexpr int Hn = Dn / 2;   // half row (floats)
constexpr int Bn = 4096;     // batch
constexpr int NCLS = 10;
constexpr int CH = 8;        // rows per chunk == waves per pass12 block
constexpr int NBLK0 = Bn / 256;         // 16 pass0 blocks
constexpr int MAXCH = Bn / CH + NCLS;   // 522 grid upper bound

// Workspace layout (float/int units). NO pre-zeroing needed:
// every slot is written exactly once by plain stores before being read.
constexpr int OFF_CEB  = 0;      // 16 floats: per-block CE sums
constexpr int OFF_CNT  = 16;     // 16*10 ints: blkcnt[b][c]
constexpr int OFF_XS   = 176;    // 1 float (zeroed by pass0 block 0)
constexpr int OFF_DONE = 177;    // 1 int   (zeroed by pass0 block 0)
constexpr int OFF_ORDB = 192;    // 16*10*256 ints: ORDB[b][c][r]
constexpr int OFF_P    = 41216;  // partials: MAXCH * 4096 floats (16B aligned)

// ---------------------------------------------------------------- pass 0
// CE + argmax + block-local class lists. 16 blocks x 256. NO global atomics.
__global__ __launch_bounds__(256) void pass0_ce_order(
    const float* __restrict__ outputs, const int* __restrict__ y,
    float* __restrict__ ws)
{
    const int t = threadIdx.x;
    const int b = blockIdx.x;
    const int i = b * 256 + t;
    const int w = t >> 6, lane = t & 63;
    int* wsi = (int*)ws;

    __shared__ int hist[NCLS];
    __shared__ float sce[4];
    if (t < NCLS) hist[t] = 0;
    __syncthreads();

    const float* o = outputs + (size_t)i * NCLS;
    float m = o[0]; int am = 0;
    #pragma unroll
    for (int k = 1; k < NCLS; ++k) { float ok = o[k]; if (ok > m) { m = ok; am = k; } }
    float se = 0.f;
    #pragma unroll
    for (int k = 0; k < NCLS; ++k) se += expf(o[k] - m);
    float ce = m + logf(se) - o[y[i]];

    int rank = atomicAdd(&hist[am], 1);              // LDS atomic only (tiny)
    wsi[OFF_ORDB + (b * NCLS + am) * 256 + rank] = i;

    #pragma unroll
    for (int off = 32; off; off >>= 1) ce += __shfl_down(ce, off, 64);
    if (lane == 0) sce[w] = ce;
    __syncthreads();

    if (t < NCLS) wsi[OFF_CNT + b * NCLS + t] = hist[t];
    if (t == 0) ws[OFF_CEB + b] = sce[0] + sce[1] + sce[2] + sce[3];
    if (b == 0 && t == 32) { ws[OFF_XS] = 0.f; wsi[OFF_DONE] = 0; }
}

// ---------------------------------------------------------------- pass 12
// R7 post-mortem: 131 KB LDS -> 1 block/CU; the block barrier exposes the
// slowest of 8 row-streams with no sibling block to fill the bubble, and
// grid 522 needs 3 scheduling rounds. Fix: HALF-ROW staging (64 KB) -> 2
// blocks/CU, 16 waves/CU, 512/522 blocks co-resident in ~one round;
// sibling blocks hide each other's straggler/barrier bubbles.
//   phase 1: stream FULL row folding (min,sum,sumsq) [moment identity,
//            exact per R6/R7]; stage only first half to LDS
//   combine half 1 (per-thread FMA over m rows) -> 8 KB partial write
//   phase 2: re-stream second half (grad is L3-resident: 67 MB << 256 MB)
//            into the same LDS; combine half 2 -> 8 KB
// All branches around barriers are block-uniform; bulk LDS atomics remain
// banned (R1/R2/R5/R6: >=138 us with them, <43 us without).
__global__ __launch_bounds__(512) void pass12_fused(
    const float* __restrict__ grad, float* __restrict__ ws)
{
    const int* wsi = (const int*)ws;
    const int t = threadIdx.x, w = t >> 6, lane = t & 63;

    __shared__ int lcnt[NBLK0 * NCLS];   // blkcnt[b][c]
    __shared__ int tot[NCLS];
    __shared__ float rows[CH][Hn];       // 64 KB half-row staging
    __shared__ float A8[CH], B8[CH];

    if (t < NBLK0 * NCLS) lcnt[t] = wsi[OFF_CNT + t];
    __syncthreads();
    if (t < NCLS) {
        int s = 0;
        #pragma unroll
        for (int bb = 0; bb < NBLK0; ++bb) s += lcnt[bb * NCLS + t];
        tot[t] = s;
    }
    __syncthreads();

    // chunk map: blockIdx.x -> (class c, global start s0, class count cnt)
    int c = -1, s0 = 0, cnt = 0;
    {
        int bidx = (int)blockIdx.x, acc = 0;
        #pragma unroll
        for (int k = 0; k < NCLS; ++k) {
            int n = tot[k];
            int nch = (n + CH - 1) / CH;
            if (c < 0 && bidx < acc + nch) { c = k; s0 = (bidx - acc) * CH; cnt = n; }
            acc += nch;
        }
    }
    if (c < 0) return;                   // block-uniform, after all barriers
    const int m = min(CH, cnt - s0);     // >=1 for any active block

    // map class-rank -> row pointer (kept in 2 SGPR-ish regs, tiny live set)
    const float4* row = nullptr;
    if (w < m) {
        int idx;
        {
            const int r = s0 + w;
            int pref = 0, src = 0, loc = 0;
            #pragma unroll
            for (int bb = 0; bb < NBLK0; ++bb) {
                int n = lcnt[bb * NCLS + c];
                if (r >= pref && r < pref + n) { src = bb; loc = r - pref; }
                pref += n;
            }
            idx = wsi[OFF_ORDB + (src * NCLS + c) * 256 + loc];
        }
        row = (const float4*)grad + (size_t)idx * (Dn / 4);

        // ---- phase 1: full-row stats stream; stage first half only
        float4* rw = (float4*)rows[w];
        float mn = 3.4e38f, sg = 0.f, sg2 = 0.f;
        #pragma unroll
        for (int k = 0; k < 16; ++k) {
            float4 v = row[k * 64 + lane];
            if (k < 8) rw[k * 64 + lane] = v;
            mn = fminf(mn, fminf(fminf(v.x, v.y), fminf(v.z, v.w)));
            sg += (v.x + v.y) + (v.z + v.w);
            sg2 = fmaf(v.x, v.x, fmaf(v.y, v.y, fmaf(v.z, v.z, fmaf(v.w, v.w, sg2))));
        }
        #pragma unroll
        for (int off = 1; off < 64; off <<= 1) {
            mn  = fminf(mn, __shfl_xor(mn, off, 64));
            sg  += __shfl_xor(sg, off, 64);
            sg2 += __shfl_xor(sg2, off, 64);
        }
        if (lane == 0) {
            // ss = sum(g-mn)^2 via moment identity (verified exact, R6/R7)
            const float ss = fmaf(mn, fmaf((float)Dn, mn, -2.f * sg), sg2);
            const float a = 1.0f / sqrtf(ss);   // min-max range cancels under L2
            A8[w] = a; B8[w] = -mn * a;
        }
    }
    __syncthreads();

    float sb = 0.f;
    for (int r = 0; r < m; ++r) sb += B8[r];
    float4* Pc = (float4*)(ws + OFF_P) + (size_t)blockIdx.x * (Dn / 4);

    // ---- combine half 1: thread t owns float4-quad t of the half (512 quads)
    {
        float ox = sb, oy = sb, oz = sb, ow = sb;
        for (int r = 0; r < m; ++r) {
            float4 u = ((const float4*)rows[r])[t];
            const float a = A8[r];
            ox = fmaf(u.x, a, ox); oy = fmaf(u.y, a, oy);
            oz = fmaf(u.z, a, oz); ow = fmaf(u.w, a, ow);
        }
        Pc[t] = make_float4(ox, oy, oz, ow);
    }
    __syncthreads();                     // combine-half1 reads done

    // ---- phase 2: re-stream second half (L3-hit) into the same LDS
    if (w < m) {
        float4* rw = (float4*)rows[w];
        #pragma unroll
        for (int k = 8; k < 16; ++k)
            rw[(k - 8) * 64 + lane] = row[k * 64 + lane];
    }
    __syncthreads();

    // ---- combine half 2
    {
        float ox = sb, oy = sb, oz = sb, ow = sb;
        for (int r = 0; r < m; ++r) {
            float4 u = ((const float4*)rows[r])[t];
            const float a = A8[r];
            ox = fmaf(u.x, a, ox); oy = fmaf(u.y, a, oy);
            oz = fmaf(u.z, a, oz); ow = fmaf(u.w, a, ow);
        }
        Pc[512 + t] = make_float4(ox, oy, oz, ow);
    }
}

// ---------------------------------------------------------------- pass 34
// Reduce chunk partials per class (~52 chunks/class, 8.6 MB total, freshly
// written -> L2/L3-warm), square, sum; last block finalizes. 64-thread
// blocks, grid 640: spreads the latency-bound chunk loop over all CUs with
// ~52 independent loads/thread of ILP.
__global__ __launch_bounds__(64) void pass34_final(
    float* __restrict__ ws, float* __restrict__ out)
{
    const int t = threadIdx.x;
    const int idx = blockIdx.x * 64 + t;     // 0 .. 40959
    const int c = idx >> 12;                 // class (uniform per block)
    const int j = idx & (Dn - 1);
    const int* wsi = (const int*)ws;

    __shared__ int tot[NCLS];
    if (t < NCLS) {
        int s = 0;
        #pragma unroll
        for (int bb = 0; bb < NBLK0; ++bb) s += wsi[OFF_CNT + bb * NCLS + t];
        tot[t] = s;
    }
    __syncthreads();

    int cs = 0, ce2 = 0;
    {
        int acc = 0;
        #pragma unroll
        for (int k = 0; k < NCLS; ++k) {
            int nch = (tot[k] + CH - 1) / CH;
            if (k == c) { cs = acc; ce2 = acc + nch; }
            acc += nch;
        }
    }

    const float* P = ws + OFF_P;
    float s = 0.f;
    int ch = cs;
    for (; ch + 4 <= ce2; ch += 4)
        s += P[(size_t)(ch + 0) * Dn + j] + P[(size_t)(ch + 1) * Dn + j]
           + P[(size_t)(ch + 2) * Dn + j] + P[(size_t)(ch + 3) * Dn + j];
    for (; ch < ce2; ++ch) s += P[(size_t)ch * Dn + j];
    float p = s * s;

    #pragma unroll
    for (int off = 32; off; off >>= 1) p += __shfl_down(p, off, 64);
    if (t == 0) {
        atomicAdd(&ws[OFF_XS], p);
        __threadfence();
        int ticket = atomicAdd(&((int*)ws)[OFF_DONE], 1);
        if (ticket == (NCLS * Dn / 64) - 1) {
            float xs = atomicAdd(&ws[OFF_XS], 0.0f);   // coherent read
            double n2 = 0.0;
            #pragma unroll
            for (int k = 0; k < NCLS; ++k) { double nc = (double)tot[k]; n2 += nc * nc; }
            double cesum = 0.0;
            #pragma unroll
            for (int k = 0; k < NBLK0; ++k) cesum += (double)ws[OFF_CEB + k];
            double xloss = (n2 - (double)xs) / (2.0 * (double)Bn);
            out[0] = (float)(cesum / (double)Bn + xloss);
        }
    }
}

extern "C" void kernel_launch(void* const* d_in, const int* in_sizes, int n_in,
                              void* d_out, int out_size, void* d_ws, size_t ws_size,
                              hipStream_t stream)
{
    const float* outputs = (const float*)d_in[0];   // [4096,10] f32
    const float* grad    = (const float*)d_in[1];   // [4096,1,64,64] f32
    const int*   y       = (const int*)d_in[2];     // [4096] i32
    float* ws  = (float*)d_ws;
    float* out = (float*)d_out;

    pass0_ce_order<<<NBLK0, 256, 0, stream>>>(outputs, y, ws);
    pass12_fused<<<MAXCH, 512, 0, stream>>>(grad, ws);
    pass34_final<<<NCLS * Dn / 64, 64, 0, stream>>>(ws, out);
}